// Round 12
// baseline (684.030 us; speedup 1.0000x reference)
//
#include <hip/hip_runtime.h>
#include <hip/hip_bf16.h>

// ---------------------------------------------------------------------------
// GNN regression: per timestep t: 3x GCNConv(relu) then edge-MLP head.
//   edge head: relu(concat(x[s],x[d],ea)@We + be) . Wg
//            = relu(u[s] + v[d] + ea@We_ea + be) . Wg,  u=x@We[:128], v=x@We[128:256]
//   GCN agg via CSR-by-dst gather; agg(xW)=agg(x)W; row scale dinv folded in.
// NOTE: reference rebinds W1=W2 after t=0 (`W1 = W2; W1 = W1`).
// R2..R9: edge_mlp 375->62us (LDS-stage, bf16, fp8); MFMA matmuls ~7us.
// R10: fused gather+matmul, 613us; fused_gm 70us x6, all pipes idle.
// R11: global idx prefetch pipeline REGRESSED (74us): vmcnt is in-order, so
//   waiting on idx loads (issued after rows) force-drains the row pipeline.
//   Three designs all pin at ~12G random rows/s; edge_mlp does 25.8G/s with
//   idx in LDS.
// R12: idx loads moved OFF vmcnt: block's CSR slice is contiguous ->
//   coalesced stage into LDS once; hot loop reads idx via ds_read (lgkmcnt)
//   and keeps only row loads on vmcnt -> true vmcnt(8) pipeline, 8-16 rows
//   in flight. Overflow >2048 idx falls back to global (66-sigma event).
// ---------------------------------------------------------------------------

typedef __attribute__((ext_vector_type(8))) short bf16x8;
typedef __attribute__((ext_vector_type(4))) float f32x4;
typedef __attribute__((ext_vector_type(2))) float f32x2;

__device__ __forceinline__ unsigned short f2bf(float f) {
    union { float f; unsigned int u; } v; v.f = f;
    unsigned int r = v.u + 0x7fffu + ((v.u >> 16) & 1u);  // RNE
    return (unsigned short)(r >> 16);
}
__device__ __forceinline__ unsigned int pk2bf(float lo, float hi) {
    return (unsigned int)f2bf(lo) | ((unsigned int)f2bf(hi) << 16);
}
// fp8 e4m3 (OCP on gfx950) via HW converts
__device__ __forceinline__ unsigned char f2fp8(float f) {
    return (unsigned char)(__builtin_amdgcn_cvt_pk_fp8_f32(f, f, 0, false) & 0xff);
}
__device__ __forceinline__ void fp8x4(unsigned int u, float* o) {
    f32x2 lo = __builtin_amdgcn_cvt_pk_f32_fp8(u, false);
    f32x2 hi = __builtin_amdgcn_cvt_pk_f32_fp8(u, true);
    o[0] = lo[0]; o[1] = lo[1]; o[2] = hi[0]; o[3] = hi[1];
}
__device__ __forceinline__ void de16add(uint4 v, float* a) {
    float t[4];
    fp8x4(v.x, t); a[0]+=t[0]; a[1]+=t[1]; a[2]+=t[2]; a[3]+=t[3];
    fp8x4(v.y, t); a[4]+=t[0]; a[5]+=t[1]; a[6]+=t[2]; a[7]+=t[3];
    fp8x4(v.z, t); a[8]+=t[0]; a[9]+=t[1]; a[10]+=t[2]; a[11]+=t[3];
    fp8x4(v.w, t); a[12]+=t[0]; a[13]+=t[1]; a[14]+=t[2]; a[15]+=t[3];
}

__global__ void to_bf16(const float* __restrict__ in, unsigned short* __restrict__ out, int n4)
{
    int i = blockIdx.x * 256 + threadIdx.x;
    if (i < n4) {
        float4 v = ((const float4*)in)[i];
        ushort4 o;
        o.x = f2bf(v.x); o.y = f2bf(v.y); o.z = f2bf(v.z); o.w = f2bf(v.w);
        ((ushort4*)out)[i] = o;
    }
}

// Transpose weight blocks -> bf16 Wt[c*128+k], once per launch.
// y: 0:W1->T1  1:W2->T2  2:W3->T3  3:We_u->Tuv[0]  4:We_v->Tuv[128^2]
//    5:W2->Tuv[256*128]  (boundary fused kernel's extra cols = next-t conv1)
__global__ void transpose_w(
    const float* __restrict__ W1, const float* __restrict__ W2,
    const float* __restrict__ W3, const float* __restrict__ We,
    unsigned short* __restrict__ T1, unsigned short* __restrict__ T2,
    unsigned short* __restrict__ T3, unsigned short* __restrict__ Tuv)
{
    const float* src; unsigned short* dst;
    switch (blockIdx.y) {
        case 0:  src = W1;             dst = T1;               break;
        case 1:  src = W2;             dst = T2;               break;
        case 2:  src = W3;             dst = T3;               break;
        case 3:  src = We;             dst = Tuv;              break;
        case 4:  src = We + 128 * 128; dst = Tuv + 128 * 128;  break;
        default: src = W2;             dst = Tuv + 256 * 128;  break;
    }
    for (int i = blockIdx.x * 256 + threadIdx.x; i < 128 * 128; i += 256 * gridDim.x) {
        int k = i >> 7, c = i & 127;
        dst[c * 128 + k] = f2bf(src[i]);
    }
}

// ---------------- standalone MFMA matmul (t=0 conv1 only) -------------------
__global__ __launch_bounds__(256) void mfma_matmul(
    const unsigned short* __restrict__ X, const unsigned short* __restrict__ Wt,
    unsigned char* __restrict__ out, const float* __restrict__ scale, int n_rows)
{
    const int wave = threadIdx.x >> 6;
    const int lane = threadIdx.x & 63;
    const int m = lane & 15;
    const int q = lane >> 4;
    const int r = blockIdx.x * 64 + wave * 16 + m;
    const bool rv = r < n_rows;

    f32x4 acc[8];
    #pragma unroll
    for (int i = 0; i < 8; ++i) acc[i] = (f32x4){0.f, 0.f, 0.f, 0.f};

    #pragma unroll
    for (int k0 = 0; k0 < 128; k0 += 32) {
        bf16x8 a = {};
        if (rv) a = *(const bf16x8*)(X + (size_t)r * 128 + k0 + q * 8);
        #pragma unroll
        for (int ct = 0; ct < 8; ++ct) {
            bf16x8 b = *(const bf16x8*)(Wt + (ct * 16 + m) * 128 + k0 + q * 8);
            acc[ct] = __builtin_amdgcn_mfma_f32_16x16x32_bf16(a, b, acc[ct], 0, 0, 0);
        }
    }

    #pragma unroll
    for (int reg = 0; reg < 4; ++reg) {
        int gr = blockIdx.x * 64 + wave * 16 + q * 4 + reg;
        if (gr >= n_rows) continue;
        float s = scale[gr];
        #pragma unroll
        for (int ct = 0; ct < 8; ++ct)
            out[(size_t)gr * 128 + ct * 16 + m] = f2fp8(acc[ct][reg] * s);
    }
}

// ---------------- FUSED gather + matmul -------------------------------------
// 32 nodes/block, 8 lanes/node x 16 fp8-ch. Preamble: coalesced stage of the
// block's CONTIGUOUS CSR idx slice into LDS. Phase A: idx via ds_read
// (lgkmcnt), rows on vmcnt only -> true dual-batch pipeline. Phase B: MFMA.
#define FPAD 136
#define GN 32
#define IDXCAP 2048
__global__ __launch_bounds__(256) void fused_gm(
    const unsigned char* __restrict__ hs_in, const int* __restrict__ csr_src,
    const int* __restrict__ offs, const int* __restrict__ counts,
    const float* __restrict__ dinv, const float* __restrict__ bias,
    const unsigned short* __restrict__ Wt, int ncols, int uvcols,
    unsigned char* __restrict__ buv, unsigned char* __restrict__ bh, int n)
{
    __shared__ unsigned short xs[GN * FPAD];   // 8704 B
    __shared__ int idxs[IDXCAP];               // 8192 B
    const int tid = threadIdx.x;
    const int n0 = blockIdx.x * GN;
    const int nend = min(n0 + GN, n);
    const int base = offs[n0];
    const int total = offs[nend - 1] + counts[nend - 1] - base;

    // coalesced idx stage (contiguous slice of csr_src)
    const int staged = min(total, IDXCAP);
    for (int i = tid; i < staged; i += 256)
        idxs[i] = csr_src[base + i];
    __syncthreads();

    const int row = tid >> 3;                 // node-in-block 0..31
    const int node = n0 + row;
    const int c16 = (tid & 7) * 16;

    if (node < n) {
        const int loff = offs[node] - base;
        const int cnt = counts[node];
        const int* gidx = csr_src + base;     // overflow fallback

        float a[16] = {};
        de16add(*(const uint4*)(hs_in + (size_t)node * 128 + c16), a);  // self

        auto getIdx = [&](int t) -> int {
            return (t < IDXCAP) ? idxs[t] : gidx[t];
        };

        int j = 0;
        if (cnt >= 8) {
            uint4 h0[8];
            #pragma unroll
            for (int q = 0; q < 8; ++q)
                h0[q] = *(const uint4*)(hs_in + (size_t)getIdx(loff + q) * 128 + c16);
            j = 8;
            for (; j + 8 <= cnt; j += 8) {
                uint4 h1[8];
                #pragma unroll
                for (int q = 0; q < 8; ++q)
                    h1[q] = *(const uint4*)(hs_in + (size_t)getIdx(loff + j + q) * 128 + c16);
                // consume previous batch; next batch stays in flight (vmcnt(8))
                #pragma unroll
                for (int q = 0; q < 8; ++q) de16add(h0[q], a);
                #pragma unroll
                for (int q = 0; q < 8; ++q) h0[q] = h1[q];
            }
            #pragma unroll
            for (int q = 0; q < 8; ++q) de16add(h0[q], a);
        }
        for (; j < cnt; ++j)
            de16add(*(const uint4*)(hs_in + (size_t)getIdx(loff + j) * 128 + c16), a);

        float dn = dinv[node];
        #pragma unroll
        for (int i = 0; i < 4; ++i) {
            float4 bb = *(const float4*)(bias + c16 + i * 4);
            float r0 = fmaxf(fmaf(a[i*4+0], dn, bb.x), 0.f);
            float r1 = fmaxf(fmaf(a[i*4+1], dn, bb.y), 0.f);
            float r2 = fmaxf(fmaf(a[i*4+2], dn, bb.z), 0.f);
            float r3 = fmaxf(fmaf(a[i*4+3], dn, bb.w), 0.f);
            *(unsigned int*)&xs[row * FPAD + c16 + i*4 + 0] = pk2bf(r0, r1);
            *(unsigned int*)&xs[row * FPAD + c16 + i*4 + 2] = pk2bf(r2, r3);
        }
    }
    __syncthreads();

    // ---- Phase B: MFMA x(LDS) @ Wt -> fp8 outputs --------------------------
    const int wave = tid >> 6;
    const int lane = tid & 63;
    const int m = lane & 15;
    const int q = lane >> 4;
    const int rt = (wave & 1) * 16;           // row-tile base (0 or 16)
    const int nct = ncols >> 4;
    const int half = nct >> 1;
    const int ct0 = (wave >> 1) * half;

    for (int ci = 0; ci < half; ++ci) {
        const int ct = ct0 + ci;
        f32x4 acc = (f32x4){0.f, 0.f, 0.f, 0.f};
        #pragma unroll
        for (int k0 = 0; k0 < 128; k0 += 32) {
            bf16x8 a = *(const bf16x8*)&xs[(rt + m) * FPAD + k0 + q * 8];
            bf16x8 b = *(const bf16x8*)(Wt + (size_t)(ct * 16 + m) * 128 + k0 + q * 8);
            acc = __builtin_amdgcn_mfma_f32_16x16x32_bf16(a, b, acc, 0, 0, 0);
        }
        const int col = ct * 16 + m;
        #pragma unroll
        for (int reg = 0; reg < 4; ++reg) {
            int nd = n0 + rt + q * 4 + reg;
            if (nd >= n) continue;
            if (col < uvcols)
                buv[(size_t)nd * 256 + col] = f2fp8(acc[reg]);
            else
                bh[(size_t)nd * 128 + col - uvcols] = f2fp8(acc[reg] * dinv[nd]);
        }
    }
}

// acc += sum_e relu(u[src_e] + v[dst_e] + ea_e@We_ea + be) . Wg   (uv fp8)
#define EM_CHUNK 256
__global__ __launch_bounds__(256) void edge_mlp(
    const unsigned char* __restrict__ uv, const int* __restrict__ src,
    const int* __restrict__ dst, const float* __restrict__ ea,
    const float* __restrict__ We_e, const float* __restrict__ be,
    const float* __restrict__ Wg, float* __restrict__ acc, int E)
{
    const int tid  = threadIdx.x;
    const int lane = tid & 31;
    const int g    = tid >> 5;
    const int c4   = lane * 4;

    __shared__ float eas[EM_CHUNK * 7];
    __shared__ int   ss[EM_CHUNK];
    __shared__ int   ds[EM_CHUNK];
    __shared__ float red[256];

    float4 w[7];
    #pragma unroll
    for (int i = 0; i < 7; ++i)
        w[i] = *(const float4*)(We_e + i * 128 + c4);
    const float4 be4 = *(const float4*)(be + c4);
    const float4 wg4 = *(const float4*)(Wg + c4);

    float4 part = make_float4(0.f, 0.f, 0.f, 0.f);

    for (int base = blockIdx.x * EM_CHUNK; base < E; base += gridDim.x * EM_CHUNK) {
        const int nch = min(EM_CHUNK, E - base);
        for (int i = tid; i < nch * 7; i += 256)
            eas[i] = ea[(size_t)base * 7 + i];
        for (int i = tid; i < nch; i += 256) {
            ss[i] = src[base + i];
            ds[i] = dst[base + i];
        }
        __syncthreads();

        auto ev = [&](int j) {
            unsigned int us = *(const unsigned int*)(uv + (size_t)ss[j] * 256 + c4);
            unsigned int vs = *(const unsigned int*)(uv + (size_t)ds[j] * 256 + 128 + c4);
            float uf[4], vf[4];
            fp8x4(us, uf); fp8x4(vs, vf);
            const float* eav = &eas[j * 7];
            float4 val;
            val.x = uf[0] + vf[0] + be4.x;
            val.y = uf[1] + vf[1] + be4.y;
            val.z = uf[2] + vf[2] + be4.z;
            val.w = uf[3] + vf[3] + be4.w;
            #pragma unroll
            for (int i = 0; i < 7; ++i) {
                float e = eav[i];
                val.x = fmaf(e, w[i].x, val.x);
                val.y = fmaf(e, w[i].y, val.y);
                val.z = fmaf(e, w[i].z, val.z);
                val.w = fmaf(e, w[i].w, val.w);
            }
            part.x += fmaxf(val.x, 0.f);
            part.y += fmaxf(val.y, 0.f);
            part.z += fmaxf(val.z, 0.f);
            part.w += fmaxf(val.w, 0.f);
        };

        int j = g;
        for (; j + 32 <= nch; j += 32) {
            ev(j); ev(j + 8); ev(j + 16); ev(j + 24);
        }
        for (; j < nch; j += 8)
            ev(j);
        __syncthreads();
    }

    float p = part.x * wg4.x + part.y * wg4.y + part.z * wg4.z + part.w * wg4.w;
    red[tid] = p;
    __syncthreads();
    for (int s = 128; s > 0; s >>= 1) {
        if (tid < s) red[tid] += red[tid + s];
        __syncthreads();
    }
    if (tid == 0) atomicAdd(acc, red[0]);
}

// ---------------- CSR build ----------------
__global__ void count_edges(const int* __restrict__ dst, int* __restrict__ counts, int E)
{
    int e = blockIdx.x * 256 + threadIdx.x;
    if (e < E) atomicAdd(&counts[dst[e]], 1);
}

__global__ void compute_dinv(const int* __restrict__ counts, float* __restrict__ dinv, int n)
{
    int i = blockIdx.x * 256 + threadIdx.x;
    if (i < n) dinv[i] = rsqrtf((float)counts[i] + 1.0f);
}

__global__ void scan1(const int* __restrict__ counts, int* __restrict__ scanned,
                      int* __restrict__ btot, int n)
{
    __shared__ int sh[256];
    int i = blockIdx.x * 256 + threadIdx.x;
    int v = (i < n) ? counts[i] : 0;
    sh[threadIdx.x] = v;
    __syncthreads();
    for (int off = 1; off < 256; off <<= 1) {
        int t = (threadIdx.x >= off) ? sh[threadIdx.x - off] : 0;
        __syncthreads();
        sh[threadIdx.x] += t;
        __syncthreads();
    }
    if (i < n) scanned[i] = sh[threadIdx.x] - v;  // exclusive
    if (threadIdx.x == 255) btot[blockIdx.x] = sh[255];
}

__global__ void scan2(int* __restrict__ btot, int nb)
{
    __shared__ int sh[256];
    int v = (threadIdx.x < nb) ? btot[threadIdx.x] : 0;
    sh[threadIdx.x] = v;
    __syncthreads();
    for (int off = 1; off < 256; off <<= 1) {
        int t = (threadIdx.x >= off) ? sh[threadIdx.x - off] : 0;
        __syncthreads();
        sh[threadIdx.x] += t;
        __syncthreads();
    }
    if (threadIdx.x < nb) btot[threadIdx.x] = sh[threadIdx.x] - v;  // exclusive
}

__global__ void scan3(const int* __restrict__ scanned, const int* __restrict__ btot,
                      int* __restrict__ offs, int* __restrict__ cursor, int n)
{
    int i = blockIdx.x * 256 + threadIdx.x;
    if (i < n) {
        int o = scanned[i] + btot[blockIdx.x];
        offs[i] = o;
        cursor[i] = o;
    }
}

__global__ void fill_csr(const int* __restrict__ src, const int* __restrict__ dst,
                         int* __restrict__ cursor, int* __restrict__ csr_src, int E)
{
    int e = blockIdx.x * 256 + threadIdx.x;
    if (e < E) {
        int slot = atomicAdd(&cursor[dst[e]], 1);
        csr_src[slot] = src[e];
    }
}

__global__ void write_out(const float* __restrict__ acc, const float* __restrict__ bg,
                          float* __restrict__ out, float invE, int T)
{
    int t = threadIdx.x;
    if (t < T) out[t] = acc[t] * invE + bg[0];
}

// ---------------------------------------------------------------------------

extern "C" void kernel_launch(void* const* d_in, const int* in_sizes, int n_in,
                              void* d_out, int out_size, void* d_ws, size_t ws_size,
                              hipStream_t stream)
{
    const float* x   = (const float*)d_in[0];
    const int*  eidx = (const int*)d_in[1];
    const float* ea  = (const float*)d_in[2];
    const float* W1  = (const float*)d_in[3];
    const float* b1  = (const float*)d_in[4];
    const float* W2  = (const float*)d_in[5];
    const float* b2  = (const float*)d_in[6];
    const float* W3  = (const float*)d_in[7];
    const float* b3  = (const float*)d_in[8];
    const float* We  = (const float*)d_in[9];
    const float* be  = (const float*)d_in[10];
    const float* Wg  = (const float*)d_in[11];
    const float* bg  = (const float*)d_in[12];

    const int N = in_sizes[0] / 128;
    const int E = in_sizes[1] / 2;
    const int T = in_sizes[2] / (E * 7);
    const int* src = eidx;
    const int* dst = eidx + E;

    char* wsp = (char*)d_ws;
    auto alloc = [&](size_t bytes) -> char* {
        char* p = wsp;
        wsp += (bytes + 255) / 256 * 256;
        return p;
    };
    int*   counts  = (int*)alloc((size_t)N * 4);
    int*   offs    = (int*)alloc((size_t)N * 4);
    int*   cursor  = (int*)alloc((size_t)N * 4);
    int*   scanned = (int*)alloc((size_t)N * 4);
    int*   btot    = (int*)alloc(1024);
    int*   csr_src = (int*)alloc((size_t)E * 4);
    float* dinv    = (float*)alloc((size_t)N * 4);
    float* acc     = (float*)alloc(256);
    unsigned short* X0  = (unsigned short*)alloc((size_t)N * 128 * 2);  // x bf16
    unsigned char*  Bh0 = (unsigned char*)alloc((size_t)N * 128);       // hs fp8 (dbuf)
    unsigned char*  Bh1 = (unsigned char*)alloc((size_t)N * 128);
    unsigned char*  Buv = (unsigned char*)alloc((size_t)N * 256);       // uv fp8
    unsigned short* T1  = (unsigned short*)alloc(128 * 128 * 2);        // W^T bf16
    unsigned short* T2  = (unsigned short*)alloc(128 * 128 * 2);
    unsigned short* T3  = (unsigned short*)alloc(128 * 128 * 2);
    unsigned short* Tuv = (unsigned short*)alloc(384 * 128 * 2);        // [We_u|We_v|W2]^T

    hipMemsetAsync(counts, 0, (size_t)N * 4, stream);
    hipMemsetAsync(acc, 0, (size_t)T * 4, stream);

    to_bf16<<<(N * 128 / 4 + 255) / 256, 256, 0, stream>>>(x, X0, N * 128 / 4);
    transpose_w<<<dim3(8, 6), 256, 0, stream>>>(W1, W2, W3, We, T1, T2, T3, Tuv);

    count_edges<<<(E + 255) / 256, 256, 0, stream>>>(dst, counts, E);
    compute_dinv<<<(N + 255) / 256, 256, 0, stream>>>(counts, dinv, N);
    const int nb = (N + 255) / 256;
    scan1<<<nb, 256, 0, stream>>>(counts, scanned, btot, N);
    scan2<<<1, 256, 0, stream>>>(btot, nb);
    scan3<<<nb, 256, 0, stream>>>(scanned, btot, offs, cursor, N);
    fill_csr<<<(E + 255) / 256, 256, 0, stream>>>(src, dst, cursor, csr_src, E);

    const int mmb = (N + 63) / 64;
    const int fgb = (N + GN - 1) / GN;
    const int emb = (E + EM_CHUNK - 1) / EM_CHUNK;

    unsigned char* hcur = Bh0;
    unsigned char* hnxt = Bh1;

    for (int t = 0; t < T; ++t) {
        if (t == 0) {
            // hs1 = (x @ W1) * dinv   (only timestep that uses W1)
            mfma_matmul<<<mmb, 256, 0, stream>>>(X0, T1, hcur, dinv, N);
        }
        // x2 = relu(agg(hs1)*dinv + b1); hs2 = (x2 @ W2) * dinv
        fused_gm<<<fgb, 256, 0, stream>>>(hcur, csr_src, offs, counts, dinv, b1,
                                          T2, 128, 0, Buv, hnxt, N);
        { unsigned char* tmp = hcur; hcur = hnxt; hnxt = tmp; }
        // x3' = relu(agg(hs2)*dinv + b2); hs3 = (x3' @ W3) * dinv
        fused_gm<<<fgb, 256, 0, stream>>>(hcur, csr_src, offs, counts, dinv, b2,
                                          T3, 128, 0, Buv, hnxt, N);
        { unsigned char* tmp = hcur; hcur = hnxt; hnxt = tmp; }
        // x3 = relu(agg(hs3)*dinv + b3); uv = x3 @ [We_u|We_v];
        // if not last timestep also hs1' = (x3 @ W2) * dinv  (W1:=W2 rebind)
        bool last = (t == T - 1);
        fused_gm<<<fgb, 256, 0, stream>>>(hcur, csr_src, offs, counts, dinv, b3,
                                          Tuv, last ? 256 : 384, 256, Buv, hnxt, N);
        if (!last) { unsigned char* tmp = hcur; hcur = hnxt; hnxt = tmp; }

        edge_mlp<<<emb, 256, 0, stream>>>(Buv, src, dst, ea + (size_t)t * E * 7,
                                          We + 256 * 128, be, Wg, acc + t, E);
    }
    write_out<<<1, 64, 0, stream>>>(acc, bg, (float*)d_out, 1.0f / (float)E, T);
}

// Round 13
// 585.643 us; speedup vs baseline: 1.1680x; 1.1680x over previous
//
#include <hip/hip_runtime.h>
#include <hip/hip_bf16.h>

// ---------------------------------------------------------------------------
// GNN regression: per timestep t: 3x GCNConv(relu) then edge-MLP head.
//   edge head: relu(concat(x[s],x[d],ea)@We + be) . Wg
//            = relu(u[s] + v[d] + ea@We_ea + be) . Wg,  u=x@We[:128], v=x@We[128:256]
//   GCN agg via CSR-by-dst gather; agg(xW)=agg(x)W; row scale dinv folded in.
// NOTE: reference rebinds W1=W2 after t=0 (`W1 = W2; W1 = W1`).
// R2..R9: edge_mlp 375->62us (LDS-stage, bf16, fp8); MFMA matmuls ~7us.
// R10: fused gather+matmul 613us (fused_gm 70us x6; all pipes idle).
// R11/R12: pipeline attempts REGRESSED (74/84us). Mechanism isolated:
//   vmcnt is in-order, so idx loads from global drain the row pipeline
//   (R10/R11); R12 fixed that but block-wide idx staging (barrier) + 88 VGPR
//   + fallback branch cost more than the pipeline gained.
// R13: per-GROUP idx staging: each 8-lane group stages its own node's idx
//   list into LDS (no block barrier; lgkmcnt only; stride-72 rows kill the
//   8-way bank conflict), cap 64 (P[deg>64] ~ 1e-20), global tail fallback.
//   Hot loop: ping-pong quads, idx via ds_read -> rows are the ONLY vmcnt
//   items -> 1 latency trip per 8 rows, h regs 32 VGPR, target <=64 total.
// ---------------------------------------------------------------------------

typedef __attribute__((ext_vector_type(8))) short bf16x8;
typedef __attribute__((ext_vector_type(4))) float f32x4;
typedef __attribute__((ext_vector_type(2))) float f32x2;

__device__ __forceinline__ unsigned short f2bf(float f) {
    union { float f; unsigned int u; } v; v.f = f;
    unsigned int r = v.u + 0x7fffu + ((v.u >> 16) & 1u);  // RNE
    return (unsigned short)(r >> 16);
}
__device__ __forceinline__ unsigned int pk2bf(float lo, float hi) {
    return (unsigned int)f2bf(lo) | ((unsigned int)f2bf(hi) << 16);
}
// fp8 e4m3 (OCP on gfx950) via HW converts
__device__ __forceinline__ unsigned char f2fp8(float f) {
    return (unsigned char)(__builtin_amdgcn_cvt_pk_fp8_f32(f, f, 0, false) & 0xff);
}
__device__ __forceinline__ void fp8x4(unsigned int u, float* o) {
    f32x2 lo = __builtin_amdgcn_cvt_pk_f32_fp8(u, false);
    f32x2 hi = __builtin_amdgcn_cvt_pk_f32_fp8(u, true);
    o[0] = lo[0]; o[1] = lo[1]; o[2] = hi[0]; o[3] = hi[1];
}
__device__ __forceinline__ void de16add(uint4 v, float* a) {
    float t[4];
    fp8x4(v.x, t); a[0]+=t[0]; a[1]+=t[1]; a[2]+=t[2]; a[3]+=t[3];
    fp8x4(v.y, t); a[4]+=t[0]; a[5]+=t[1]; a[6]+=t[2]; a[7]+=t[3];
    fp8x4(v.z, t); a[8]+=t[0]; a[9]+=t[1]; a[10]+=t[2]; a[11]+=t[3];
    fp8x4(v.w, t); a[12]+=t[0]; a[13]+=t[1]; a[14]+=t[2]; a[15]+=t[3];
}

__global__ void to_bf16(const float* __restrict__ in, unsigned short* __restrict__ out, int n4)
{
    int i = blockIdx.x * 256 + threadIdx.x;
    if (i < n4) {
        float4 v = ((const float4*)in)[i];
        ushort4 o;
        o.x = f2bf(v.x); o.y = f2bf(v.y); o.z = f2bf(v.z); o.w = f2bf(v.w);
        ((ushort4*)out)[i] = o;
    }
}

// Transpose weight blocks -> bf16 Wt[c*128+k], once per launch.
// y: 0:W1->T1  1:W2->T2  2:W3->T3  3:We_u->Tuv[0]  4:We_v->Tuv[128^2]
//    5:W2->Tuv[256*128]  (boundary fused kernel's extra cols = next-t conv1)
__global__ void transpose_w(
    const float* __restrict__ W1, const float* __restrict__ W2,
    const float* __restrict__ W3, const float* __restrict__ We,
    unsigned short* __restrict__ T1, unsigned short* __restrict__ T2,
    unsigned short* __restrict__ T3, unsigned short* __restrict__ Tuv)
{
    const float* src; unsigned short* dst;
    switch (blockIdx.y) {
        case 0:  src = W1;             dst = T1;               break;
        case 1:  src = W2;             dst = T2;               break;
        case 2:  src = W3;             dst = T3;               break;
        case 3:  src = We;             dst = Tuv;              break;
        case 4:  src = We + 128 * 128; dst = Tuv + 128 * 128;  break;
        default: src = W2;             dst = Tuv + 256 * 128;  break;
    }
    for (int i = blockIdx.x * 256 + threadIdx.x; i < 128 * 128; i += 256 * gridDim.x) {
        int k = i >> 7, c = i & 127;
        dst[c * 128 + k] = f2bf(src[i]);
    }
}

// ---------------- standalone MFMA matmul (t=0 conv1 only) -------------------
__global__ __launch_bounds__(256) void mfma_matmul(
    const unsigned short* __restrict__ X, const unsigned short* __restrict__ Wt,
    unsigned char* __restrict__ out, const float* __restrict__ scale, int n_rows)
{
    const int wave = threadIdx.x >> 6;
    const int lane = threadIdx.x & 63;
    const int m = lane & 15;
    const int q = lane >> 4;
    const int r = blockIdx.x * 64 + wave * 16 + m;
    const bool rv = r < n_rows;

    f32x4 acc[8];
    #pragma unroll
    for (int i = 0; i < 8; ++i) acc[i] = (f32x4){0.f, 0.f, 0.f, 0.f};

    #pragma unroll
    for (int k0 = 0; k0 < 128; k0 += 32) {
        bf16x8 a = {};
        if (rv) a = *(const bf16x8*)(X + (size_t)r * 128 + k0 + q * 8);
        #pragma unroll
        for (int ct = 0; ct < 8; ++ct) {
            bf16x8 b = *(const bf16x8*)(Wt + (ct * 16 + m) * 128 + k0 + q * 8);
            acc[ct] = __builtin_amdgcn_mfma_f32_16x16x32_bf16(a, b, acc[ct], 0, 0, 0);
        }
    }

    #pragma unroll
    for (int reg = 0; reg < 4; ++reg) {
        int gr = blockIdx.x * 64 + wave * 16 + q * 4 + reg;
        if (gr >= n_rows) continue;
        float s = scale[gr];
        #pragma unroll
        for (int ct = 0; ct < 8; ++ct)
            out[(size_t)gr * 128 + ct * 16 + m] = f2fp8(acc[ct][reg] * s);
    }
}

// ---------------- FUSED gather + matmul -------------------------------------
// 32 nodes/block, 8 lanes/node x 16 fp8-ch. Per-GROUP idx staging into LDS
// (no block barrier; idx reads in hot loop are ds_read -> lgkmcnt, rows are
// the only vmcnt items). Ping-pong quads keep 4-8 rows in flight. Phase B:
// MFMA vs Wt.
#define FPAD 136
#define GN 32
#define ICAP 64
#define ISTR 72   // idx row stride (dwords); 72 mod 32 = 8 -> 2-way max (free)
__global__ __launch_bounds__(256) void fused_gm(
    const unsigned char* __restrict__ hs_in, const int* __restrict__ csr_src,
    const int* __restrict__ offs, const int* __restrict__ counts,
    const float* __restrict__ dinv, const float* __restrict__ bias,
    const unsigned short* __restrict__ Wt, int ncols, int uvcols,
    unsigned char* __restrict__ buv, unsigned char* __restrict__ bh, int n)
{
    __shared__ unsigned short xs[GN * FPAD];   // 8704 B
    __shared__ int idxl[GN * ISTR];            // 9216 B
    const int tid = threadIdx.x;
    const int row = tid >> 3;                  // node-in-block 0..31
    const int node = blockIdx.x * GN + row;
    const int lg = tid & 7;                    // lane-in-group
    const int c16 = lg * 16;

    if (node < n) {
        const int off = offs[node];
        const int cnt = counts[node];
        const int cap = min(cnt, ICAP);

        // group-local idx stage: 8 lanes, coalesced stride-1 global reads.
        // Only this group reads these slots -> no barrier, lgkmcnt only.
        for (int j = lg; j < cap; j += 8)
            idxl[row * ISTR + j] = csr_src[off + j];

        float a[16] = {};
        de16add(*(const uint4*)(hs_in + (size_t)node * 128 + c16), a);  // self

        int j = 0;
        if (cap >= 4) {
            uint4 hA[4], hB[4];
            #pragma unroll
            for (int q = 0; q < 4; ++q)
                hA[q] = *(const uint4*)(hs_in + (size_t)idxl[row * ISTR + q] * 128 + c16);
            j = 4;
            for (; j + 4 <= cap; j += 4) {
                #pragma unroll
                for (int q = 0; q < 4; ++q)
                    hB[q] = *(const uint4*)(hs_in + (size_t)idxl[row * ISTR + j + q] * 128 + c16);
                #pragma unroll
                for (int q = 0; q < 4; ++q) de16add(hA[q], a);   // hB in flight
                #pragma unroll
                for (int q = 0; q < 4; ++q) hA[q] = hB[q];
            }
            #pragma unroll
            for (int q = 0; q < 4; ++q) de16add(hA[q], a);
        }
        for (; j < cap; ++j)
            de16add(*(const uint4*)(hs_in + (size_t)idxl[row * ISTR + j] * 128 + c16), a);
        for (; j < cnt; ++j)   // >ICAP overflow: effectively never (P~1e-20)
            de16add(*(const uint4*)(hs_in + (size_t)csr_src[off + j] * 128 + c16), a);

        float dn = dinv[node];
        #pragma unroll
        for (int i = 0; i < 4; ++i) {
            float4 bb = *(const float4*)(bias + c16 + i * 4);
            float r0 = fmaxf(fmaf(a[i*4+0], dn, bb.x), 0.f);
            float r1 = fmaxf(fmaf(a[i*4+1], dn, bb.y), 0.f);
            float r2 = fmaxf(fmaf(a[i*4+2], dn, bb.z), 0.f);
            float r3 = fmaxf(fmaf(a[i*4+3], dn, bb.w), 0.f);
            *(unsigned int*)&xs[row * FPAD + c16 + i*4 + 0] = pk2bf(r0, r1);
            *(unsigned int*)&xs[row * FPAD + c16 + i*4 + 2] = pk2bf(r2, r3);
        }
    }
    __syncthreads();

    // ---- Phase B: MFMA x(LDS) @ Wt -> fp8 outputs --------------------------
    const int wave = tid >> 6;
    const int lane = tid & 63;
    const int m = lane & 15;
    const int q = lane >> 4;
    const int rt = (wave & 1) * 16;           // row-tile base (0 or 16)
    const int nct = ncols >> 4;
    const int half = nct >> 1;
    const int ct0 = (wave >> 1) * half;

    for (int ci = 0; ci < half; ++ci) {
        const int ct = ct0 + ci;
        f32x4 acc = (f32x4){0.f, 0.f, 0.f, 0.f};
        #pragma unroll
        for (int k0 = 0; k0 < 128; k0 += 32) {
            bf16x8 a = *(const bf16x8*)&xs[(rt + m) * FPAD + k0 + q * 8];
            bf16x8 b = *(const bf16x8*)(Wt + (size_t)(ct * 16 + m) * 128 + k0 + q * 8);
            acc = __builtin_amdgcn_mfma_f32_16x16x32_bf16(a, b, acc, 0, 0, 0);
        }
        const int col = ct * 16 + m;
        #pragma unroll
        for (int reg = 0; reg < 4; ++reg) {
            int nd = blockIdx.x * GN + rt + q * 4 + reg;
            if (nd >= n) continue;
            if (col < uvcols)
                buv[(size_t)nd * 256 + col] = f2fp8(acc[reg]);
            else
                bh[(size_t)nd * 128 + col - uvcols] = f2fp8(acc[reg] * dinv[nd]);
        }
    }
}

// acc += sum_e relu(u[src_e] + v[dst_e] + ea_e@We_ea + be) . Wg   (uv fp8)
#define EM_CHUNK 256
__global__ __launch_bounds__(256) void edge_mlp(
    const unsigned char* __restrict__ uv, const int* __restrict__ src,
    const int* __restrict__ dst, const float* __restrict__ ea,
    const float* __restrict__ We_e, const float* __restrict__ be,
    const float* __restrict__ Wg, float* __restrict__ acc, int E)
{
    const int tid  = threadIdx.x;
    const int lane = tid & 31;
    const int g    = tid >> 5;
    const int c4   = lane * 4;

    __shared__ float eas[EM_CHUNK * 7];
    __shared__ int   ss[EM_CHUNK];
    __shared__ int   ds[EM_CHUNK];
    __shared__ float red[256];

    float4 w[7];
    #pragma unroll
    for (int i = 0; i < 7; ++i)
        w[i] = *(const float4*)(We_e + i * 128 + c4);
    const float4 be4 = *(const float4*)(be + c4);
    const float4 wg4 = *(const float4*)(Wg + c4);

    float4 part = make_float4(0.f, 0.f, 0.f, 0.f);

    for (int base = blockIdx.x * EM_CHUNK; base < E; base += gridDim.x * EM_CHUNK) {
        const int nch = min(EM_CHUNK, E - base);
        for (int i = tid; i < nch * 7; i += 256)
            eas[i] = ea[(size_t)base * 7 + i];
        for (int i = tid; i < nch; i += 256) {
            ss[i] = src[base + i];
            ds[i] = dst[base + i];
        }
        __syncthreads();

        auto ev = [&](int j) {
            unsigned int us = *(const unsigned int*)(uv + (size_t)ss[j] * 256 + c4);
            unsigned int vs = *(const unsigned int*)(uv + (size_t)ds[j] * 256 + 128 + c4);
            float uf[4], vf[4];
            fp8x4(us, uf); fp8x4(vs, vf);
            const float* eav = &eas[j * 7];
            float4 val;
            val.x = uf[0] + vf[0] + be4.x;
            val.y = uf[1] + vf[1] + be4.y;
            val.z = uf[2] + vf[2] + be4.z;
            val.w = uf[3] + vf[3] + be4.w;
            #pragma unroll
            for (int i = 0; i < 7; ++i) {
                float e = eav[i];
                val.x = fmaf(e, w[i].x, val.x);
                val.y = fmaf(e, w[i].y, val.y);
                val.z = fmaf(e, w[i].z, val.z);
                val.w = fmaf(e, w[i].w, val.w);
            }
            part.x += fmaxf(val.x, 0.f);
            part.y += fmaxf(val.y, 0.f);
            part.z += fmaxf(val.z, 0.f);
            part.w += fmaxf(val.w, 0.f);
        };

        int j = g;
        for (; j + 32 <= nch; j += 32) {
            ev(j); ev(j + 8); ev(j + 16); ev(j + 24);
        }
        for (; j < nch; j += 8)
            ev(j);
        __syncthreads();
    }

    float p = part.x * wg4.x + part.y * wg4.y + part.z * wg4.z + part.w * wg4.w;
    red[tid] = p;
    __syncthreads();
    for (int s = 128; s > 0; s >>= 1) {
        if (tid < s) red[tid] += red[tid + s];
        __syncthreads();
    }
    if (tid == 0) atomicAdd(acc, red[0]);
}

// ---------------- CSR build ----------------
__global__ void count_edges(const int* __restrict__ dst, int* __restrict__ counts, int E)
{
    int e = blockIdx.x * 256 + threadIdx.x;
    if (e < E) atomicAdd(&counts[dst[e]], 1);
}

__global__ void compute_dinv(const int* __restrict__ counts, float* __restrict__ dinv, int n)
{
    int i = blockIdx.x * 256 + threadIdx.x;
    if (i < n) dinv[i] = rsqrtf((float)counts[i] + 1.0f);
}

__global__ void scan1(const int* __restrict__ counts, int* __restrict__ scanned,
                      int* __restrict__ btot, int n)
{
    __shared__ int sh[256];
    int i = blockIdx.x * 256 + threadIdx.x;
    int v = (i < n) ? counts[i] : 0;
    sh[threadIdx.x] = v;
    __syncthreads();
    for (int off = 1; off < 256; off <<= 1) {
        int t = (threadIdx.x >= off) ? sh[threadIdx.x - off] : 0;
        __syncthreads();
        sh[threadIdx.x] += t;
        __syncthreads();
    }
    if (i < n) scanned[i] = sh[threadIdx.x] - v;  // exclusive
    if (threadIdx.x == 255) btot[blockIdx.x] = sh[255];
}

__global__ void scan2(int* __restrict__ btot, int nb)
{
    __shared__ int sh[256];
    int v = (threadIdx.x < nb) ? btot[threadIdx.x] : 0;
    sh[threadIdx.x] = v;
    __syncthreads();
    for (int off = 1; off < 256; off <<= 1) {
        int t = (threadIdx.x >= off) ? sh[threadIdx.x - off] : 0;
        __syncthreads();
        sh[threadIdx.x] += t;
        __syncthreads();
    }
    if (threadIdx.x < nb) btot[threadIdx.x] = sh[threadIdx.x] - v;  // exclusive
}

__global__ void scan3(const int* __restrict__ scanned, const int* __restrict__ btot,
                      int* __restrict__ offs, int* __restrict__ cursor, int n)
{
    int i = blockIdx.x * 256 + threadIdx.x;
    if (i < n) {
        int o = scanned[i] + btot[blockIdx.x];
        offs[i] = o;
        cursor[i] = o;
    }
}

__global__ void fill_csr(const int* __restrict__ src, const int* __restrict__ dst,
                         int* __restrict__ cursor, int* __restrict__ csr_src, int E)
{
    int e = blockIdx.x * 256 + threadIdx.x;
    if (e < E) {
        int slot = atomicAdd(&cursor[dst[e]], 1);
        csr_src[slot] = src[e];
    }
}

__global__ void write_out(const float* __restrict__ acc, const float* __restrict__ bg,
                          float* __restrict__ out, float invE, int T)
{
    int t = threadIdx.x;
    if (t < T) out[t] = acc[t] * invE + bg[0];
}

// ---------------------------------------------------------------------------

extern "C" void kernel_launch(void* const* d_in, const int* in_sizes, int n_in,
                              void* d_out, int out_size, void* d_ws, size_t ws_size,
                              hipStream_t stream)
{
    const float* x   = (const float*)d_in[0];
    const int*  eidx = (const int*)d_in[1];
    const float* ea  = (const float*)d_in[2];
    const float* W1  = (const float*)d_in[3];
    const float* b1  = (const float*)d_in[4];
    const float* W2  = (const float*)d_in[5];
    const float* b2  = (const float*)d_in[6];
    const float* W3  = (const float*)d_in[7];
    const float* b3  = (const float*)d_in[8];
    const float* We  = (const float*)d_in[9];
    const float* be  = (const float*)d_in[10];
    const float* Wg  = (const float*)d_in[11];
    const float* bg  = (const float*)d_in[12];

    const int N = in_sizes[0] / 128;
    const int E = in_sizes[1] / 2;
    const int T = in_sizes[2] / (E * 7);
    const int* src = eidx;
    const int* dst = eidx + E;

    char* wsp = (char*)d_ws;
    auto alloc = [&](size_t bytes) -> char* {
        char* p = wsp;
        wsp += (bytes + 255) / 256 * 256;
        return p;
    };
    int*   counts  = (int*)alloc((size_t)N * 4);
    int*   offs    = (int*)alloc((size_t)N * 4);
    int*   cursor  = (int*)alloc((size_t)N * 4);
    int*   scanned = (int*)alloc((size_t)N * 4);
    int*   btot    = (int*)alloc(1024);
    int*   csr_src = (int*)alloc((size_t)E * 4);
    float* dinv    = (float*)alloc((size_t)N * 4);
    float* acc     = (float*)alloc(256);
    unsigned short* X0  = (unsigned short*)alloc((size_t)N * 128 * 2);  // x bf16
    unsigned char*  Bh0 = (unsigned char*)alloc((size_t)N * 128);       // hs fp8 (dbuf)
    unsigned char*  Bh1 = (unsigned char*)alloc((size_t)N * 128);
    unsigned char*  Buv = (unsigned char*)alloc((size_t)N * 256);       // uv fp8
    unsigned short* T1  = (unsigned short*)alloc(128 * 128 * 2);        // W^T bf16
    unsigned short* T2  = (unsigned short*)alloc(128 * 128 * 2);
    unsigned short* T3  = (unsigned short*)alloc(128 * 128 * 2);
    unsigned short* Tuv = (unsigned short*)alloc(384 * 128 * 2);        // [We_u|We_v|W2]^T

    hipMemsetAsync(counts, 0, (size_t)N * 4, stream);
    hipMemsetAsync(acc, 0, (size_t)T * 4, stream);

    to_bf16<<<(N * 128 / 4 + 255) / 256, 256, 0, stream>>>(x, X0, N * 128 / 4);
    transpose_w<<<dim3(8, 6), 256, 0, stream>>>(W1, W2, W3, We, T1, T2, T3, Tuv);

    count_edges<<<(E + 255) / 256, 256, 0, stream>>>(dst, counts, E);
    compute_dinv<<<(N + 255) / 256, 256, 0, stream>>>(counts, dinv, N);
    const int nb = (N + 255) / 256;
    scan1<<<nb, 256, 0, stream>>>(counts, scanned, btot, N);
    scan2<<<1, 256, 0, stream>>>(btot, nb);
    scan3<<<nb, 256, 0, stream>>>(scanned, btot, offs, cursor, N);
    fill_csr<<<(E + 255) / 256, 256, 0, stream>>>(src, dst, cursor, csr_src, E);

    const int mmb = (N + 63) / 64;
    const int fgb = (N + GN - 1) / GN;
    const int emb = (E + EM_CHUNK - 1) / EM_CHUNK;

    unsigned char* hcur = Bh0;
    unsigned char* hnxt = Bh1;

    for (int t = 0; t < T; ++t) {
        if (t == 0) {
            // hs1 = (x @ W1) * dinv   (only timestep that uses W1)
            mfma_matmul<<<mmb, 256, 0, stream>>>(X0, T1, hcur, dinv, N);
        }
        // x2 = relu(agg(hs1)*dinv + b1); hs2 = (x2 @ W2) * dinv
        fused_gm<<<fgb, 256, 0, stream>>>(hcur, csr_src, offs, counts, dinv, b1,
                                          T2, 128, 0, Buv, hnxt, N);
        { unsigned char* tmp = hcur; hcur = hnxt; hnxt = tmp; }
        // x3' = relu(agg(hs2)*dinv + b2); hs3 = (x3' @ W3) * dinv
        fused_gm<<<fgb, 256, 0, stream>>>(hcur, csr_src, offs, counts, dinv, b2,
                                          T3, 128, 0, Buv, hnxt, N);
        { unsigned char* tmp = hcur; hcur = hnxt; hnxt = tmp; }
        // x3 = relu(agg(hs3)*dinv + b3); uv = x3 @ [We_u|We_v];
        // if not last timestep also hs1' = (x3 @ W2) * dinv  (W1:=W2 rebind)
        bool last = (t == T - 1);
        fused_gm<<<fgb, 256, 0, stream>>>(hcur, csr_src, offs, counts, dinv, b3,
                                          Tuv, last ? 256 : 384, 256, Buv, hnxt, N);
        if (!last) { unsigned char* tmp = hcur; hcur = hnxt; hnxt = tmp; }

        edge_mlp<<<emb, 256, 0, stream>>>(Buv, src, dst, ea + (size_t)t * E * 7,
                                          We + 256 * 128, be, Wg, acc + t, E);
    }
    write_out<<<1, 64, 0, stream>>>(acc, bg, (float*)d_out, 1.0f / (float)E, T);
}